// Round 16
// baseline (233.503 us; speedup 1.0000x reference)
//
#include <hip/hip_runtime.h>

typedef __attribute__((ext_vector_type(8))) __bf16 bf16x8;
typedef __attribute__((ext_vector_type(4))) float f32x4;

#define N_SAMP 256
#define DIM    2048
#define NCENT  32000
#define INV_T  14.285714285714285714f   // 1 / 0.07
#define NWG    1000                      // one 256x32 panel (256 KB contiguous) per block
#define NSTEP  64                        // K / 32

// A pre-packed in MFMA-fragment order (R13-verified):
//   byte = ktile*16384 + grp*1024 + lane*16   (grp=row>>4, lane=(row&15)|(((k>>3)&3)<<4))
// B LDS tile: K-major [u=0..255][row 0..31, padded to 33] of 16B units (u = k>>3).
//   addr = u*528 + row*16 (+8 for odd k-half). 528-byte stride rotates bank quads
//   by 4 per unit -> both ds_write_b64 (stage) and ds_read_b128 (frag) are uniform.

// ---- kernel 1: normalize feats -> bf16 fragment-packed; zero d_acc ----
__global__ __launch_bounds__(256) void norm_kernel(const float* __restrict__ feats,
                                                   char* __restrict__ fnorm_pk,
                                                   float* __restrict__ d_acc) {
    int row = blockIdx.x;
    int tid = threadIdx.x;
    if (row < 16) d_acc[row * 256 + tid] = 0.f;   // zero 8 slots x 512 floats
    const float* src = feats + (size_t)row * DIM;
    float4 v0 = reinterpret_cast<const float4*>(src)[2 * tid];
    float4 v1 = reinterpret_cast<const float4*>(src)[2 * tid + 1];
    float ss = v0.x * v0.x + v0.y * v0.y + v0.z * v0.z + v0.w * v0.w
             + v1.x * v1.x + v1.y * v1.y + v1.z * v1.z + v1.w * v1.w;
    #pragma unroll
    for (int off = 1; off < 64; off <<= 1) ss += __shfl_xor(ss, off, 64);
    __shared__ float wsum[4];
    if ((tid & 63) == 0) wsum[tid >> 6] = ss;
    __syncthreads();
    float inv = 1.0f / sqrtf(wsum[0] + wsum[1] + wsum[2] + wsum[3]);
    bf16x8 o;
    o[0] = (__bf16)(v0.x * inv); o[1] = (__bf16)(v0.y * inv);
    o[2] = (__bf16)(v0.z * inv); o[3] = (__bf16)(v0.w * inv);
    o[4] = (__bf16)(v1.x * inv); o[5] = (__bf16)(v1.y * inv);
    o[6] = (__bf16)(v1.z * inv); o[7] = (__bf16)(v1.w * inv);
    int tile = tid >> 2, ksub = tid & 3;
    int grp  = row >> 4;
    int lane = (row & 15) | (ksub << 4);
    *reinterpret_cast<bf16x8*>(fnorm_pk
        + ((size_t)tile * 16 + grp) * 1024 + lane * 16) = o;
}

// ---- kernel 2: M-chunk GEMM. 1000 blocks x 256 thr (4 waves, wave = 64 rows x 32 cols) ----
// Stage the block's whole 32-row panel ROW-SEQUENTIALLY (8 KB bursts), one barrier,
// then a barrier-free 64-step K-loop: A packed-direct (L2), B from LDS.
__global__ __launch_bounds__(256) void sims_kernel(
    const char* __restrict__ fnorm_pk, const float* __restrict__ centers,
    const int* __restrict__ labels, const int* __restrict__ camids,
    float* __restrict__ d_acc, float* __restrict__ d_own)
{
    __shared__ __align__(16) char sB[256 * 528];   // 132 KB K-major swizzle-free tile

    const int tid  = threadIdx.x;
    const int wave = tid >> 6;
    const int lane = tid & 63;
    const int l15  = lane & 15;
    const int lhi  = lane >> 4;

    const int nb    = blockIdx.x;        // 0..999
    const int cbase = nb * 32;

    // ---- stage: 32 rows x 8 KB, fully sequential per row ----
    {
        const int lhalf = lane & 1;
        #pragma unroll
        for (int rr = 0; rr < 8; ++rr) {
            int row = wave * 8 + rr;
            const float4* rp = reinterpret_cast<const float4*>(
                centers + (size_t)(cbase + row) * DIM);
            float4 v0 = rp[lane];
            float4 v1 = rp[lane + 64];
            float4 v2 = rp[lane + 128];
            float4 v3 = rp[lane + 192];
            float4 v4 = rp[lane + 256];
            float4 v5 = rp[lane + 320];
            float4 v6 = rp[lane + 384];
            float4 v7 = rp[lane + 448];
            char* base = &sB[(size_t)(lane >> 1) * 528 + row * 16 + lhalf * 8];
            #pragma unroll
            for (int j = 0; j < 8; ++j) {
                float4 v = j == 0 ? v0 : j == 1 ? v1 : j == 2 ? v2 : j == 3 ? v3
                         : j == 4 ? v4 : j == 5 ? v5 : j == 6 ? v6 : v7;
                short4 o;
                o.x = (short)__builtin_bit_cast(unsigned short, (__bf16)v.x);
                o.y = (short)__builtin_bit_cast(unsigned short, (__bf16)v.y);
                o.z = (short)__builtin_bit_cast(unsigned short, (__bf16)v.z);
                o.w = (short)__builtin_bit_cast(unsigned short, (__bf16)v.w);
                *reinterpret_cast<short4*>(base + (size_t)j * 32 * 528) = o;
            }
        }
    }
    __syncthreads();   // the ONLY barrier

    // ---- K-loop: 64 steps, no barriers (tile is read-only) ----
    f32x4 acc[4][2] = {};
    const char* apk = fnorm_pk + (size_t)(wave * 4) * 1024 + lane * 16;

    auto loadA = [&](int t, bf16x8 (&af)[4]) {
        const char* p = apk + (size_t)t * 16384;
        af[0] = *reinterpret_cast<const bf16x8*>(p);
        af[1] = *reinterpret_cast<const bf16x8*>(p + 1024);
        af[2] = *reinterpret_cast<const bf16x8*>(p + 2048);
        af[3] = *reinterpret_cast<const bf16x8*>(p + 3072);
    };
    auto loadB = [&](int t, bf16x8 (&bf)[2]) {
        int u = t * 4 + lhi;
        bf[0] = *reinterpret_cast<const bf16x8*>(&sB[(size_t)u * 528 + l15 * 16]);
        bf[1] = *reinterpret_cast<const bf16x8*>(&sB[(size_t)u * 528 + (16 + l15) * 16]);
    };
    auto mm = [&](const bf16x8 (&af)[4], const bf16x8 (&bf)[2]) {
        #pragma unroll
        for (int mi = 0; mi < 4; ++mi)
            #pragma unroll
            for (int ni = 0; ni < 2; ++ni)
                acc[mi][ni] = __builtin_amdgcn_mfma_f32_16x16x32_bf16(
                    af[mi], bf[ni], acc[mi][ni], 0, 0, 0);
    };

    bf16x8 afA[4], afB[4], bfA[2], bfB[2];
    loadA(0, afA); loadB(0, bfA);
    for (int t = 0; t < NSTEP; t += 2) {
        if (t + 1 < NSTEP) { loadA(t + 1, afB); loadB(t + 1, bfB); }
        mm(afA, bfA);
        if (t + 2 < NSTEP) { loadA(t + 2, afA); loadB(t + 2, bfA); }
        if (t + 1 < NSTEP) mm(afB, bfB);
    }

    // ---- epilogue: exp + masks + per-sample partial denominators ----
    float* slot_acc = d_acc + (nb & 7) * 512;
    #pragma unroll
    for (int mi = 0; mi < 4; ++mi) {
        #pragma unroll
        for (int r = 0; r < 4; ++r) {
            int i   = wave * 64 + mi * 16 + lhi * 4 + r;
            int lab = labels[i], cam = camids[i];
            int oidx = lab * 8 + cam;
            float pi = 0.f, pj = 0.f;
            #pragma unroll
            for (int ni = 0; ni < 2; ++ni) {
                int c = cbase + ni * 16 + l15;
                float s = acc[mi][ni][r] * INV_T;
                float e = __expf(s);
                if ((l15 & 7) == cam) pi += e;          // c % 8 == cam
                bool ol = ((c >> 3) == lab);
                bool hard = (!ol) && (c < ((c < lab * 8) ? 50 : 58));
                if (ol || hard) pj += e;
                if (c == oidx) d_own[i] = s;
            }
            #pragma unroll
            for (int off = 1; off < 16; off <<= 1) {
                pi += __shfl_xor(pi, off, 64);
                pj += __shfl_xor(pj, off, 64);
            }
            if (l15 == 0) {
                atomicAdd(&slot_acc[i], pi);
                atomicAdd(&slot_acc[N_SAMP + i], pj);
            }
        }
    }
}

// ---------------- kernel 3: finalize (segment means + output) ----------------
__global__ __launch_bounds__(256) void finalize_kernel(
    const float* __restrict__ d_acc, const float* __restrict__ d_own,
    const int* __restrict__ labels, const int* __restrict__ camids,
    float* __restrict__ out, int out_size)
{
    __shared__ int s_lab[N_SAMP], s_cam[N_SAMP];
    __shared__ float wsum[8];
    int tid = threadIdx.x;
    s_lab[tid] = labels[tid];
    s_cam[tid] = camids[tid];
    __syncthreads();
    int myl = s_lab[tid], myc = s_cam[tid];
    int nl = 0, nc = 0;
    for (int j = 0; j < N_SAMP; ++j) {
        nl += (s_lab[j] == myl);
        nc += (s_cam[j] == myc);
    }
    float di = 0.f, dj = 0.f;
    #pragma unroll
    for (int s = 0; s < 8; ++s) {
        di += d_acc[s * 512 + tid];
        dj += d_acc[s * 512 + 256 + tid];
    }
    float own = d_own[tid];
    float li = own - logf(di);
    float lj = own - logf(dj);
    float a = li / (float)nc;   // sum_i loss_i / n_cam == sum over cams of per-cam mean
    float b = lj / (float)nl;
    #pragma unroll
    for (int off = 1; off < 64; off <<= 1) {
        a += __shfl_xor(a, off, 64);
        b += __shfl_xor(b, off, 64);
    }
    if ((tid & 63) == 0) { wsum[tid >> 6] = a; wsum[4 + (tid >> 6)] = b; }
    __syncthreads();
    if (tid == 0) {
        float sa = wsum[0] + wsum[1] + wsum[2] + wsum[3];
        float sb = wsum[4] + wsum[5] + wsum[6] + wsum[7];
        out[0] = -sa;
        if (out_size > 1) out[1] = -0.5f * sb;   // LAMDA = 0.5
    }
}

extern "C" void kernel_launch(void* const* d_in, const int* in_sizes, int n_in,
                              void* d_out, int out_size, void* d_ws, size_t ws_size,
                              hipStream_t stream) {
    const float* feats   = (const float*)d_in[0];
    const float* centers = (const float*)d_in[1];
    const int*   labels  = (const int*)d_in[2];
    const int*   camids  = (const int*)d_in[3];
    float* out = (float*)d_out;

    char*  fnorm_pk = (char*)d_ws;                                   // 1 MB packed
    float* d_acc    = (float*)((char*)d_ws + (size_t)1048576);       // 8 slots x 512
    float* d_own    = d_acc + 8 * 2 * N_SAMP;                        // 256

    norm_kernel<<<N_SAMP, 256, 0, stream>>>(feats, fnorm_pk, d_acc);
    sims_kernel<<<NWG, 256, 0, stream>>>(fnorm_pk, centers, labels, camids, d_acc, d_own);
    finalize_kernel<<<1, 256, 0, stream>>>(d_acc, d_own, labels, camids, out, out_size);
}

// Round 17
// 134.160 us; speedup vs baseline: 1.7405x; 1.7405x over previous
//
#include <hip/hip_runtime.h>

typedef __attribute__((ext_vector_type(8))) __bf16 bf16x8;
typedef __attribute__((ext_vector_type(4))) float f32x4;

#define N_SAMP 256
#define DIM    2048
#define NCENT  32000
#define INV_T  14.285714285714285714f   // 1 / 0.07
#define NWG    500                       // one 256x64 tile per block
#define NSTEP  64                        // K / BK = 2048 / 32

// A pre-packed in MFMA-fragment order (R13-verified):
//   byte = ktile*16384 + grp*1024 + lane*16  (ktile=k>>5, grp=row>>4, lane=(row&15)|(((k>>3)&3)<<4))
// B LDS tile (4 KB): 64 rows x 32 bf16. Linear ds_write_b128 at tid*16 (0 conflicts);
//   read at byte = pair*128 + slot*16, pair=row>>1, slot=(((row&1)<<2)|c8)^(pair&7)
//   -> 64 distinct 16B units per wave read (R12-verified 0 conflicts).

// ---- kernel 1: normalize feats -> bf16 fragment-packed; zero d_acc ----
__global__ __launch_bounds__(256) void norm_kernel(const float* __restrict__ feats,
                                                   char* __restrict__ fnorm_pk,
                                                   float* __restrict__ d_acc) {
    int row = blockIdx.x;
    int tid = threadIdx.x;
    if (row < 16) d_acc[row * 256 + tid] = 0.f;   // zero 8 slots x 512 floats
    const float* src = feats + (size_t)row * DIM;
    float4 v0 = reinterpret_cast<const float4*>(src)[2 * tid];
    float4 v1 = reinterpret_cast<const float4*>(src)[2 * tid + 1];
    float ss = v0.x * v0.x + v0.y * v0.y + v0.z * v0.z + v0.w * v0.w
             + v1.x * v1.x + v1.y * v1.y + v1.z * v1.z + v1.w * v1.w;
    #pragma unroll
    for (int off = 1; off < 64; off <<= 1) ss += __shfl_xor(ss, off, 64);
    __shared__ float wsum[4];
    if ((tid & 63) == 0) wsum[tid >> 6] = ss;
    __syncthreads();
    float inv = 1.0f / sqrtf(wsum[0] + wsum[1] + wsum[2] + wsum[3]);
    bf16x8 o;
    o[0] = (__bf16)(v0.x * inv); o[1] = (__bf16)(v0.y * inv);
    o[2] = (__bf16)(v0.z * inv); o[3] = (__bf16)(v0.w * inv);
    o[4] = (__bf16)(v1.x * inv); o[5] = (__bf16)(v1.y * inv);
    o[6] = (__bf16)(v1.z * inv); o[7] = (__bf16)(v1.w * inv);
    int tile = tid >> 2, ksub = tid & 3;
    int grp  = row >> 4;
    int lane = (row & 15) | (ksub << 4);
    *reinterpret_cast<bf16x8*>(fnorm_pk
        + ((size_t)tile * 16 + grp) * 1024 + lane * 16) = o;
}

// ---- kernel 2: 256x64 tile, 4 waves (wave = 64 rows x 64 cols, acc 4x4) ----
// A packed-direct from L2 (no LDS); B double-buffered 4KB LDS tiles, linear
// write / swizzled read; depth-2 named sets; raw s_barrier + lgkmcnt(0)-only
// drain; issue order B-then-A so compute's A-wait keeps next B in flight.
// 8 KB LDS + <=128 VGPR -> 4 blocks/CU: 4 independent barrier domains.
__global__ __launch_bounds__(256, 4) void sims_kernel(
    const char* __restrict__ fnorm_pk, const float* __restrict__ centers,
    const int* __restrict__ labels, const int* __restrict__ camids,
    float* __restrict__ d_acc, float* __restrict__ d_own)
{
    __shared__ __align__(16) char sB[2][4096];

    const int tid  = threadIdx.x;
    const int wave = tid >> 6;
    const int lane = tid & 63;
    const int l15  = lane & 15;
    const int lhi  = lane >> 4;

    const int nb    = blockIdx.x;        // 0..499
    const int cbase = nb * 64;

    f32x4 acc[4][4] = {};

    const float4* bsrc = reinterpret_cast<const float4*>(centers);
    const char*   apk  = fnorm_pk + (size_t)wave * 4096 + lane * 16;

    // B staging map: thread -> physical 16B unit tid; inverse-swizzle -> (row,c8)
    const int bP = tid >> 3, bs = tid & 7;
    const int bu = bs ^ (bP & 7);
    const int brow = 2 * bP + (bu >> 2);
    const int bc8  = bu & 3;
    const size_t bbase = (size_t)(cbase + brow) * 512 + bc8 * 2;

    auto issueB = [&](int T, float4& f0, float4& f1) {
        f0 = bsrc[bbase + T * 8];
        f1 = bsrc[bbase + T * 8 + 1];
    };
    auto wrbufB = [&](int buf, const float4& f0, const float4& f1) {
        bf16x8 o;
        o[0] = (__bf16)f0.x; o[1] = (__bf16)f0.y; o[2] = (__bf16)f0.z; o[3] = (__bf16)f0.w;
        o[4] = (__bf16)f1.x; o[5] = (__bf16)f1.y; o[6] = (__bf16)f1.z; o[7] = (__bf16)f1.w;
        *reinterpret_cast<bf16x8*>(&sB[buf][tid * 16]) = o;   // linear: conflict-free
    };
    auto issueA = [&](int T, bf16x8 (&af)[4]) {
        const char* p = apk + (size_t)T * 16384;
        af[0] = *reinterpret_cast<const bf16x8*>(p);
        af[1] = *reinterpret_cast<const bf16x8*>(p + 1024);
        af[2] = *reinterpret_cast<const bf16x8*>(p + 2048);
        af[3] = *reinterpret_cast<const bf16x8*>(p + 3072);
    };
    auto compute = [&](int buf, const bf16x8 (&af)[4]) {
        bf16x8 bf[4];
        #pragma unroll
        for (int ni = 0; ni < 4; ++ni) {
            int row = ni * 16 + l15, pair = row >> 1;
            int slot = (((row & 1) << 2) | lhi) ^ (pair & 7);
            bf[ni] = *reinterpret_cast<const bf16x8*>(&sB[buf][pair * 128 + slot * 16]);
        }
        #pragma unroll
        for (int mi = 0; mi < 4; ++mi)
            #pragma unroll
            for (int ni = 0; ni < 4; ++ni)
                acc[mi][ni] = __builtin_amdgcn_mfma_f32_16x16x32_bf16(
                    af[mi], bf[ni], acc[mi][ni], 0, 0, 0);
    };
    #define BAR() do { asm volatile("s_waitcnt lgkmcnt(0)" ::: "memory"); \
                       __builtin_amdgcn_s_barrier(); } while (0)

    float4 b0S0, b1S0, b0S1, b1S1;
    bf16x8 afA[4], afB[4];

    issueB(0, b0S0, b1S0);
    issueB(1, b0S1, b1S1);
    issueA(0, afA);
    wrbufB(0, b0S0, b1S0);
    BAR();
    for (int t = 0; t < NSTEP; t += 2) {
        if (t + 2 < NSTEP) issueB(t + 2, b0S0, b1S0);
        issueA(t + 1, afB);
        compute(0, afA);
        wrbufB(1, b0S1, b1S1);           // B(t+1) already drained by afA wait
        BAR();
        if (t + 3 < NSTEP) issueB(t + 3, b0S1, b1S1);
        if (t + 2 < NSTEP) issueA(t + 2, afA);
        compute(1, afB);
        if (t + 2 < NSTEP) {
            wrbufB(0, b0S0, b1S0);
            BAR();
        }
    }

    // ---- epilogue: exp + masks + per-sample partial denominators ----
    float* slot_acc = d_acc + (nb & 7) * 512;
    #pragma unroll
    for (int mi = 0; mi < 4; ++mi) {
        #pragma unroll
        for (int r = 0; r < 4; ++r) {
            int i   = wave * 64 + mi * 16 + lhi * 4 + r;
            int lab = labels[i], cam = camids[i];
            int oidx = lab * 8 + cam;
            float pi = 0.f, pj = 0.f;
            #pragma unroll
            for (int ni = 0; ni < 4; ++ni) {
                int c = cbase + ni * 16 + l15;
                float s = acc[mi][ni][r] * INV_T;
                float e = __expf(s);
                if ((l15 & 7) == cam) pi += e;          // c % 8 == cam
                bool ol = ((c >> 3) == lab);
                bool hard = (!ol) && (c < ((c < lab * 8) ? 50 : 58));
                if (ol || hard) pj += e;
                if (c == oidx) d_own[i] = s;
            }
            #pragma unroll
            for (int off = 1; off < 16; off <<= 1) {
                pi += __shfl_xor(pi, off, 64);
                pj += __shfl_xor(pj, off, 64);
            }
            if (l15 == 0) {
                atomicAdd(&slot_acc[i], pi);
                atomicAdd(&slot_acc[N_SAMP + i], pj);
            }
        }
    }
}

// ---------------- kernel 3: finalize (segment means + output) ----------------
__global__ __launch_bounds__(256) void finalize_kernel(
    const float* __restrict__ d_acc, const float* __restrict__ d_own,
    const int* __restrict__ labels, const int* __restrict__ camids,
    float* __restrict__ out, int out_size)
{
    __shared__ int s_lab[N_SAMP], s_cam[N_SAMP];
    __shared__ float wsum[8];
    int tid = threadIdx.x;
    s_lab[tid] = labels[tid];
    s_cam[tid] = camids[tid];
    __syncthreads();
    int myl = s_lab[tid], myc = s_cam[tid];
    int nl = 0, nc = 0;
    for (int j = 0; j < N_SAMP; ++j) {
        nl += (s_lab[j] == myl);
        nc += (s_cam[j] == myc);
    }
    float di = 0.f, dj = 0.f;
    #pragma unroll
    for (int s = 0; s < 8; ++s) {
        di += d_acc[s * 512 + tid];
        dj += d_acc[s * 512 + 256 + tid];
    }
    float own = d_own[tid];
    float li = own - logf(di);
    float lj = own - logf(dj);
    float a = li / (float)nc;   // sum_i loss_i / n_cam == sum over cams of per-cam mean
    float b = lj / (float)nl;
    #pragma unroll
    for (int off = 1; off < 64; off <<= 1) {
        a += __shfl_xor(a, off, 64);
        b += __shfl_xor(b, off, 64);
    }
    if ((tid & 63) == 0) { wsum[tid >> 6] = a; wsum[4 + (tid >> 6)] = b; }
    __syncthreads();
    if (tid == 0) {
        float sa = wsum[0] + wsum[1] + wsum[2] + wsum[3];
        float sb = wsum[4] + wsum[5] + wsum[6] + wsum[7];
        out[0] = -sa;
        if (out_size > 1) out[1] = -0.5f * sb;   // LAMDA = 0.5
    }
}

extern "C" void kernel_launch(void* const* d_in, const int* in_sizes, int n_in,
                              void* d_out, int out_size, void* d_ws, size_t ws_size,
                              hipStream_t stream) {
    const float* feats   = (const float*)d_in[0];
    const float* centers = (const float*)d_in[1];
    const int*   labels  = (const int*)d_in[2];
    const int*   camids  = (const int*)d_in[3];
    float* out = (float*)d_out;

    char*  fnorm_pk = (char*)d_ws;                                   // 1 MB packed
    float* d_acc    = (float*)((char*)d_ws + (size_t)1048576);       // 8 slots x 512
    float* d_own    = d_acc + 8 * 2 * N_SAMP;                        // 256

    norm_kernel<<<N_SAMP, 256, 0, stream>>>(feats, fnorm_pk, d_acc);
    sims_kernel<<<NWG, 256, 0, stream>>>(fnorm_pk, centers, labels, camids, d_acc, d_own);
    finalize_kernel<<<1, 256, 0, stream>>>(d_acc, d_own, labels, camids, out, out_size);
}